// Round 13
// baseline (161.175 us; speedup 1.0000x reference)
//
#include <hip/hip_runtime.h>
#include <math.h>

typedef unsigned short u16;
typedef unsigned int u32;
typedef __attribute__((ext_vector_type(8))) short bf16x8;   // 8 bf16 = 4 VGPR (MFMA A/B frag)
typedef __attribute__((ext_vector_type(4))) float f32x4;    // MFMA C/D frag

__device__ __forceinline__ u16 f32_to_bf16(float f) {
    u32 u = __float_as_uint(f);
    u32 r = u + 0x7FFFu + ((u >> 16) & 1u);   // round-to-nearest-even
    return (u16)(r >> 16);
}
__device__ __forceinline__ u32 pack2(u16 a, u16 b) { return (u32)a | ((u32)b << 16); }

// RNE-rounded bf16 bits (bf16 value in HIGH 16 of result)
__device__ __forceinline__ u32 rne_bits(float f) {
    u32 u = __float_as_uint(f);
    return u + 0x7FFFu + ((u >> 16) & 1u);
}

// fast tanh / sigmoid via hardware exp
__device__ __forceinline__ float fast_tanh(float x) {
    float e = __expf(2.f * x);
    return 1.f - 2.f / (e + 1.f);
}

// ---------------- quantum gate helpers (prep only; precise libm) ----------------
template<int STRIDE>
__device__ __forceinline__ void ry_gate(float st[16], float theta) {
    float s, c;
    sincosf(theta * 0.5f, &s, &c);
#pragma unroll
    for (int i = 0; i < 16; ++i) {
        if (i & STRIDE) continue;
        float s0 = st[i], s1 = st[i | STRIDE];
        st[i]          = c * s0 - s * s1;
        st[i | STRIDE] = fmaf(s, s0, c * s1);
    }
}
template<int CS, int TS>
__device__ __forceinline__ void cnot_gate(float st[16]) {
#pragma unroll
    for (int i = 0; i < 16; ++i) {
        if ((i & CS) && !(i & TS)) {
            float tmp = st[i]; st[i] = st[i | TS]; st[i | TS] = tmp;
        }
    }
}

// ---------------- Prep: fcw transpose->bf16, w2->bf16 frag layout, circuit matrix M ----------
// whi: [f][k = op*64+oc] (k_ref = oc*16+op). w2b: [(t*64+oc)*32+ic] bf16.
__global__ __launch_bounds__(256) void prep_kernel(
    const float* __restrict__ fcw, const float* __restrict__ w2,
    const float* __restrict__ qp,
    u16* __restrict__ whi, u16* __restrict__ w2b, float* __restrict__ Mg)
{
    const int f  = blockIdx.x;         // 0..63
    const int k0 = threadIdx.x * 4;    // 0..1020
    u16 hv[4];
#pragma unroll
    for (int i = 0; i < 4; ++i) {
        int k  = k0 + i;
        int op = k >> 6, oc = k & 63;
        hv[i] = f32_to_bf16(fcw[(size_t)(oc * 16 + op) * 64 + f]);
    }
    *(uint2*)(whi + (size_t)f * 1024 + k0) = make_uint2(pack2(hv[0], hv[1]), pack2(hv[2], hv[3]));

    if (threadIdx.x < 96) {
        const int j  = threadIdx.x;
        const int ic = j / 3, t = j - ic * 3;
        w2b[(t * 64 + f) * 32 + ic] = f32_to_bf16(w2[f * 96 + j]);
    }

    if (blockIdx.x == 0 && threadIdx.x < 16) {
        const int j = threadIdx.x;
        float st[16];
#pragma unroll
        for (int i = 0; i < 16; ++i) st[i] = (i == j) ? 1.f : 0.f;
        for (int k = 0; k < 6; ++k) {
            cnot_gate<8, 4>(st);   // CNOT(0,1)
            cnot_gate<2, 1>(st);   // CNOT(2,3)
            cnot_gate<4, 2>(st);   // CNOT(1,2)
            ry_gate<8>(st, qp[k * 4 + 0]);
            ry_gate<4>(st, qp[k * 4 + 1]);
            ry_gate<2>(st, qp[k * 4 + 2]);
            ry_gate<1>(st, qp[k * 4 + 3]);
        }
#pragma unroll
        for (int i = 0; i < 16; ++i) Mg[i * 16 + j] = st[i];
    }
}

// ---------------- Fused: conv1 -> conv2(MFMA) -> fc(MFMA) -> quantum epilogue ----------------
// R13: R12's small-block design with the aliasing RACE fixed. 8 samples/block, 4096 blocks,
// 256 threads (4 waves), LDS ~24.5 KB -> 5-6 blocks/CU (VGPR permitting).
// conv2 wave = SAMPLE PAIR with FULL oc range (af[3][4] = 48 VGPR): every sample's c1T
// window reads and hT writes are same-wave in-order (R12 split oc across waves -> wave A
// clobbered windows wave B was still reading -> absmax 0.027).
// Operand-swapped conv2 MFMA (A=window, B=w2) -> D[q][oc]: pool pairs IN-LANE (no shuffles).
// fc operand-swapped (A=whi features, B=hT samples; cols 8-15 dup via lr&7, discarded).
// __launch_bounds__(256,5) -> cap 102, live ~85 (headroom; R5/R7 trap was live>cap).
// Spill canary: WRITE_SIZE must stay ~0.13 MB.
// Per-sample block in c1h (1384 u16): c1T rows p[0,34) stride 40 (halo rows 0,33 zero);
// hT aliased (same-wave read-before-write) op-chunk stride 72; hfl f32[64] at u16 1152.
__global__ __launch_bounds__(256, 5) void fused_kernel(
    const float* __restrict__ x,
    const float* __restrict__ w1, const float* __restrict__ b1,
    const u16* __restrict__ w2b, const float* __restrict__ b2,
    const u16* __restrict__ whi,
    const float* __restrict__ fcb,
    const float* __restrict__ prew, const float* __restrict__ preb,
    const float* __restrict__ postw, const float* __restrict__ postb,
    const float* __restrict__ Mg,
    float* __restrict__ out)
{
    __shared__ __align__(16) u16 c1h[8 * 1384];    // 22.1 KB
    __shared__ float prews[256];                   // 1 KB
    __shared__ float Ms[16][17];                   // 1.1 KB

    const int tid  = threadIdx.x;
    const int bs   = blockIdx.x * 8;
    const int wv   = tid >> 6, lane = tid & 63;
    const int lr   = lane & 15, lq = lane >> 4;

    // ---- stage small tables (consumed after barrier3) ----
    prews[tid] = prew[tid];
    Ms[tid >> 4][tid & 15] = Mg[tid];

    // ---- conv1 + relu + pool2 -> c1T; thread = (sample, p-row), exactly 8x32 = 256 ----
    {
        const int s1 = tid >> 5;        // 0..7
        const int pp = tid & 31;        // p = pp+1
        const float* xb = x + (size_t)(bs + s1) * 64;
        const int j = 2 * pp;
        float xm1 = (j == 0)  ? 0.f : xb[j - 1];
        float x0  = xb[j];
        float x1  = xb[j + 1];
        float xp2 = (j == 62) ? 0.f : xb[j + 2];

        u16* sbase = c1h + s1 * 1384;
        if (pp == 0 || pp == 31) {      // halo rows 0 and 33
            uint4 z = make_uint4(0, 0, 0, 0);
            uint4* zr = (uint4*)(sbase + (pp == 0 ? 0 : 33) * 40);
            zr[0] = z; zr[1] = z; zr[2] = z; zr[3] = z;
        }
        u32 row[16];
#pragma unroll
        for (int icp = 0; icp < 16; ++icp) {
            float v[2];
#pragma unroll
            for (int h2 = 0; h2 < 2; ++h2) {
                int ic = icp * 2 + h2;
                // wave-uniform indices -> scalar loads on the s-pipe
                float wa = w1[ic * 3], wb = w1[ic * 3 + 1], wc = w1[ic * 3 + 2], bb = b1[ic];
                float y0 = bb + wa * xm1 + wb * x0 + wc * x1;
                float y1 = bb + wa * x0  + wb * x1 + wc * xp2;
                v[h2] = fmaxf(fmaxf(y0, y1), 0.f);
            }
            row[icp] = __builtin_amdgcn_perm(rne_bits(v[1]), rne_bits(v[0]), 0x07060302u);
        }
        uint4* d = (uint4*)(sbase + (1 + pp) * 40);
        d[0] = make_uint4(row[0],  row[1],  row[2],  row[3]);
        d[1] = make_uint4(row[4],  row[5],  row[6],  row[7]);
        d[2] = make_uint4(row[8],  row[9],  row[10], row[11]);
        d[3] = make_uint4(row[12], row[13], row[14], row[15]);
    }

    // ---- conv2 B-operand (w2, full oc range: 48 VGPR) + bias (4 VGPR), from L2 ----
    bf16x8 af[3][4];
#pragma unroll
    for (int t = 0; t < 3; ++t)
#pragma unroll
        for (int mt = 0; mt < 4; ++mt)
            af[t][mt] = *(const bf16x8*)(w2b + (size_t)(t * 64 + mt * 16 + lr) * 32 + lq * 8);
    float biasv[4];
#pragma unroll
    for (int mt = 0; mt < 4; ++mt)
        biasv[mt] = b2[mt * 16 + lr];
    __syncthreads();   // barrier 1

    // ---- conv2 via MFMA, operand-swapped: D[q][oc], pool in-lane -> hT aliased into c1h.
    //      wave wv -> samples {2wv, 2wv+1}: reads/writes of each sample stay in ONE wave
    //      (in-order LDS, data-dependent: reads complete before writes) -> race-free. ----
#pragma unroll
    for (int nt = 0; nt < 4; ++nt) {
        const int s  = wv * 2 + (nt >> 1);
        const int qb = (nt & 1) * 16;
        const u16* bp = c1h + s * 1384 + (qb + lr) * 40 + lq * 8;
        bf16x8 bf0 = *(const bf16x8*)(bp);         // tap t=0  (A: rows q = qb+lr)
        bf16x8 bf1 = *(const bf16x8*)(bp + 40);    // t=1 (+1 row)
        bf16x8 bf2 = *(const bf16x8*)(bp + 80);    // t=2 (+2 rows)
        const int op0 = (qb >> 1) + lq * 2;        // D rows q = qb + lq*4 + r
#pragma unroll
        for (int mt = 0; mt < 4; ++mt) {           // interleaved epilogue: acc live = 4
            f32x4 cinit = {biasv[mt], biasv[mt], biasv[mt], biasv[mt]};
            f32x4 acc = __builtin_amdgcn_mfma_f32_16x16x32_bf16(bf0, af[0][mt], cinit, 0, 0, 0);
            acc = __builtin_amdgcn_mfma_f32_16x16x32_bf16(bf1, af[1][mt], acc, 0, 0, 0);
            acc = __builtin_amdgcn_mfma_f32_16x16x32_bf16(bf2, af[2][mt], acc, 0, 0, 0);
            // pool (q pairs = reg pairs) + relu, bf16 RNE, 2 u16 scatter (72-stride: conflict-free)
            float p0 = fmaxf(fmaxf(acc[0], acc[1]), 0.f);
            float p1 = fmaxf(fmaxf(acc[2], acc[3]), 0.f);
            u16* hb = c1h + s * 1384 + mt * 16 + lr;
            hb[(size_t)op0 * 72]       = (u16)(rne_bits(p0) >> 16);
            hb[(size_t)(op0 + 1) * 72] = (u16)(rne_bits(p1) >> 16);
        }
    }
    __syncthreads();   // barrier 2

    // ---- fc via MFMA, operand-swapped: A = whi (rows = features), B = hT (cols = samples;
    //      cols 8-15 duplicate cols 0-7 via lr&7, discarded). All 4 waves, B streamed once. ----
    {
        const int n0 = wv * 16;
        f32x4 facc = {0.f, 0.f, 0.f, 0.f};
        const u16* aw = whi + (size_t)(n0 + lr) * 1024 + lq * 8;
        const u16* bh = c1h + (size_t)(lr & 7) * 1384 + lq * 8;
#pragma unroll 8
        for (int kc = 0; kc < 32; ++kc) {
            bf16x8 a = *(const bf16x8*)(aw + kc * 32);
            bf16x8 b = *(const bf16x8*)(bh + (kc >> 1) * 72 + (kc & 1) * 32);
            facc = __builtin_amdgcn_mfma_f32_16x16x32_bf16(a, b, facc, 0, 0, 0);
        }
        // D[f][s]: row f = n0 + lq*4 + r, col s = lr (valid s < 8); hfl disjoint from hT
        if (lr < 8) {
            float4 fb = *(const float4*)(fcb + n0 + lq * 4);
            float* hfl = (float*)(c1h + (size_t)lr * 1384 + 1152);
            hfl[n0 + lq * 4 + 0] = fmaxf(facc[0] + fb.x, 0.f);
            hfl[n0 + lq * 4 + 1] = fmaxf(facc[1] + fb.y, 0.f);
            hfl[n0 + lq * 4 + 2] = fmaxf(facc[2] + fb.z, 0.f);
            hfl[n0 + lq * 4 + 3] = fmaxf(facc[3] + fb.w, 0.f);
        }
    }
    __syncthreads();   // barrier 3

    // ---- epilogue: 4 waves x 2 samples, 4 lanes per sample ----
    if (lane < 8) {
        const int L = lane & 3;
        const int s = wv * 2 + (lane >> 2);
        const float* hfl = (const float*)(c1h + (size_t)s * 1384 + 1152);

        float a0 = 0.f, a1 = 0.f, a2 = 0.f, a3 = 0.f;
#pragma unroll
        for (int i2 = 0; i2 < 4; ++i2) {
            float4 hv = *(const float4*)(hfl + L * 16 + i2 * 4);
#pragma unroll
            for (int c = 0; c < 4; ++c) {
                int ff = L * 16 + i2 * 4 + c;
                float4 pw = *(const float4*)&prews[ff * 4];
                float hx = (c == 0) ? hv.x : (c == 1) ? hv.y : (c == 2) ? hv.z : hv.w;
                a0 = fmaf(hx, pw.x, a0);
                a1 = fmaf(hx, pw.y, a1);
                a2 = fmaf(hx, pw.z, a2);
                a3 = fmaf(hx, pw.w, a3);
            }
        }
        a0 += __shfl_xor(a0, 1); a0 += __shfl_xor(a0, 2);
        a1 += __shfl_xor(a1, 1); a1 += __shfl_xor(a1, 2);
        a2 += __shfl_xor(a2, 1); a2 += __shfl_xor(a2, 2);
        a3 += __shfl_xor(a3, 1); a3 += __shfl_xor(a3, 2);

        const float HP = 1.5707963267948966f;
        float qin[4] = { fast_tanh(a0 + preb[0]) * HP, fast_tanh(a1 + preb[1]) * HP,
                         fast_tanh(a2 + preb[2]) * HP, fast_tanh(a3 + preb[3]) * HP };

        float va[4], vb[4];
        const float RS = 0.70710678118654752f;
#pragma unroll
        for (int w = 0; w < 4; ++w) {
            float sw, cw;
            __sincosf(qin[w] * 0.5f, &sw, &cw);
            va[w] = (cw - sw) * RS;
            vb[w] = (sw + cw) * RS;
        }
        float sv[16];
#pragma unroll
        for (int jj = 0; jj < 16; ++jj) {
            float t = (jj & 8) ? vb[0] : va[0];
            t *= (jj & 4) ? vb[1] : va[1];
            t *= (jj & 2) ? vb[2] : va[2];
            t *= (jj & 1) ? vb[3] : va[3];
            sv[jj] = t;
        }
        float z0 = 0.f, z1 = 0.f, z2 = 0.f, z3 = 0.f;
#pragma unroll
        for (int rr = 0; rr < 4; ++rr) {
            const int r = L * 4 + rr;
            float m = 0.f;
#pragma unroll
            for (int jj = 0; jj < 16; ++jj) m = fmaf(Ms[r][jj], sv[jj], m);
            float p = m * m;
            z0 += (r & 8) ? -p : p;
            z1 += (r & 4) ? -p : p;
            z2 += (r & 2) ? -p : p;
            z3 += (r & 1) ? -p : p;
        }
        z0 += __shfl_xor(z0, 1); z0 += __shfl_xor(z0, 2);
        z1 += __shfl_xor(z1, 1); z1 += __shfl_xor(z1, 2);
        z2 += __shfl_xor(z2, 1); z2 += __shfl_xor(z2, 2);
        z3 += __shfl_xor(z3, 1); z3 += __shfl_xor(z3, 2);

        if (L == 0) {
            float t = postb[0] + z0 * postw[0] + z1 * postw[1] + z2 * postw[2] + z3 * postw[3];
            out[bs + s] = 1.f / (1.f + __expf(-t));
        }
    }
}

extern "C" void kernel_launch(void* const* d_in, const int* in_sizes, int n_in,
                              void* d_out, int out_size, void* d_ws, size_t ws_size,
                              hipStream_t stream) {
    const float* x     = (const float*)d_in[0];
    const float* w1    = (const float*)d_in[1];
    const float* b1    = (const float*)d_in[2];
    const float* w2    = (const float*)d_in[3];
    const float* b2    = (const float*)d_in[4];
    const float* fcw   = (const float*)d_in[5];
    const float* fcb   = (const float*)d_in[6];
    const float* prew  = (const float*)d_in[7];
    const float* preb  = (const float*)d_in[8];
    const float* qp    = (const float*)d_in[9];
    const float* postw = (const float*)d_in[10];
    const float* postb = (const float*)d_in[11];
    float* out = (float*)d_out;

    u16*   fwhi = (u16*)d_ws;                           // 64*1024 bf16 = 128 KiB
    float* Mg   = (float*)((char*)d_ws + 131072);       // 1 KiB
    u16*   w2b  = (u16*)((char*)d_ws + 132096);         // 12 KiB

    const int B = in_sizes[0] / 64;   // 32768

    prep_kernel<<<dim3(64), dim3(256), 0, stream>>>(fcw, w2, qp, fwhi, w2b, Mg);
    fused_kernel<<<dim3(B / 8), dim3(256), 0, stream>>>(x, w1, b1, w2b, b2,
                                                        fwhi, fcb, prew, preb,
                                                        postw, postb, Mg, out);
}

// Round 14
// 144.996 us; speedup vs baseline: 1.1116x; 1.1116x over previous
//
#include <hip/hip_runtime.h>
#include <math.h>

typedef unsigned short u16;
typedef unsigned int u32;
typedef __attribute__((ext_vector_type(8))) short bf16x8;   // 8 bf16 = 4 VGPR (MFMA A/B frag)
typedef __attribute__((ext_vector_type(4))) float f32x4;    // MFMA C/D frag

__device__ __forceinline__ u16 f32_to_bf16(float f) {
    u32 u = __float_as_uint(f);
    u32 r = u + 0x7FFFu + ((u >> 16) & 1u);   // round-to-nearest-even
    return (u16)(r >> 16);
}
__device__ __forceinline__ u32 pack2(u16 a, u16 b) { return (u32)a | ((u32)b << 16); }

// RNE-rounded bf16 pair pack via v_perm
__device__ __forceinline__ u32 rne_bits(float f) {
    u32 u = __float_as_uint(f);
    return u + 0x7FFFu + ((u >> 16) & 1u);
}
__device__ __forceinline__ u32 pack_rne(float a, float b) {
    return __builtin_amdgcn_perm(rne_bits(b), rne_bits(a), 0x07060302u);
}

// fast tanh via hardware exp
__device__ __forceinline__ float fast_tanh(float x) {
    float e = __expf(2.f * x);
    return 1.f - 2.f / (e + 1.f);
}

// ---------------- quantum gate helpers (prep only; precise libm) ----------------
template<int STRIDE>
__device__ __forceinline__ void ry_gate(float st[16], float theta) {
    float s, c;
    sincosf(theta * 0.5f, &s, &c);
#pragma unroll
    for (int i = 0; i < 16; ++i) {
        if (i & STRIDE) continue;
        float s0 = st[i], s1 = st[i | STRIDE];
        st[i]          = c * s0 - s * s1;
        st[i | STRIDE] = fmaf(s, s0, c * s1);
    }
}
template<int CS, int TS>
__device__ __forceinline__ void cnot_gate(float st[16]) {
#pragma unroll
    for (int i = 0; i < 16; ++i) {
        if ((i & CS) && !(i & TS)) {
            float tmp = st[i]; st[i] = st[i | TS]; st[i | TS] = tmp;
        }
    }
}

// ---------------- Prep: fcw transpose->bf16, w2->bf16 frag layout, circuit matrix M ----------
// whi: [f][k = op*64+oc] (k_ref = oc*16+op). w2b: [(t*64+oc)*32+ic] bf16.
__global__ __launch_bounds__(256) void prep_kernel(
    const float* __restrict__ fcw, const float* __restrict__ w2,
    const float* __restrict__ qp,
    u16* __restrict__ whi, u16* __restrict__ w2b, float* __restrict__ Mg)
{
    const int f  = blockIdx.x;         // 0..63
    const int k0 = threadIdx.x * 4;    // 0..1020
    u16 hv[4];
#pragma unroll
    for (int i = 0; i < 4; ++i) {
        int k  = k0 + i;
        int op = k >> 6, oc = k & 63;
        hv[i] = f32_to_bf16(fcw[(size_t)(oc * 16 + op) * 64 + f]);
    }
    *(uint2*)(whi + (size_t)f * 1024 + k0) = make_uint2(pack2(hv[0], hv[1]), pack2(hv[2], hv[3]));

    if (threadIdx.x < 96) {
        const int j  = threadIdx.x;
        const int ic = j / 3, t = j - ic * 3;
        w2b[(t * 64 + f) * 32 + ic] = f32_to_bf16(w2[f * 96 + j]);
    }

    if (blockIdx.x == 0 && threadIdx.x < 16) {
        const int j = threadIdx.x;
        float st[16];
#pragma unroll
        for (int i = 0; i < 16; ++i) st[i] = (i == j) ? 1.f : 0.f;
        for (int k = 0; k < 6; ++k) {
            cnot_gate<8, 4>(st);   // CNOT(0,1)
            cnot_gate<2, 1>(st);   // CNOT(2,3)
            cnot_gate<4, 2>(st);   // CNOT(1,2)
            ry_gate<8>(st, qp[k * 4 + 0]);
            ry_gate<4>(st, qp[k * 4 + 1]);
            ry_gate<2>(st, qp[k * 4 + 2]);
            ry_gate<1>(st, qp[k * 4 + 3]);
        }
#pragma unroll
        for (int i = 0; i < 16; ++i) Mg[i * 16 + j] = st[i];
    }
}

// ---------------- Fused: conv1 -> conv2(MFMA) -> fc(MFMA) -> quantum epilogue ----------------
// R14 = R11 champion (32 samples/block, 1024 blocks, 1024 threads, ~91 KB LDS, 1 block/CU,
// __launch_bounds__(1024,4) loose-cap no-spill) + two provable edits:
//  (1) barrier-1 DELETED: conv1 wave wv writes exactly samples {2wv,2wv+1}; conv2 wave wv
//      reads exactly those samples -> same-wave in-order LDS (the guarantee the hT aliasing
//      already uses). Cross-wave c1T visibility is never needed.
//  (2) conv2 weight frags (af/bias2) issued BEFORE conv1 arithmetic, AFTER the x loads
//      (vmcnt is in-order: x first means conv1's wait doesn't drain the af loads) ->
//      weight-load latency hides under conv1's ~350-inst VALU chain.
// Spill canary: WRITE_SIZE must stay ~0.13 MB.
// Per-sample block in c1h (1384 u16): c1T rows p[0,34) stride 40 (halo rows 0,33 zero);
// hT aliased (same-wave read-before-write) op-chunk stride 72; hfl f32[64] at u16 1152.
__global__ __launch_bounds__(1024, 4) void fused_kernel(
    const float* __restrict__ x,
    const float* __restrict__ w1, const float* __restrict__ b1,
    const u16* __restrict__ w2b, const float* __restrict__ b2,
    const u16* __restrict__ whi,
    const float* __restrict__ fcb,
    const float* __restrict__ prew, const float* __restrict__ preb,
    const float* __restrict__ postw, const float* __restrict__ postb,
    const float* __restrict__ Mg,
    float* __restrict__ out)
{
    __shared__ __align__(16) u16 c1h[32 * 1384];   // 88.6 KB
    __shared__ float prews[256];                   // 1 KB
    __shared__ float Ms[16][17];                   // 1.1 KB

    const int tid  = threadIdx.x;
    const int bs   = blockIdx.x * 32;
    const int wv   = tid >> 6, lane = tid & 63;
    const int lr   = lane & 15, lq = lane >> 4;

    // ---- stage small tables (consumed after barrier B -> visible) ----
    if (tid < 256) {
        prews[tid] = prew[tid];
        Ms[tid >> 4][tid & 15] = Mg[tid];
    }

    // ---- x loads FIRST (vmcnt in-order: conv1's wait won't drain later af loads) ----
    const int s1 = tid >> 5;        // 0..31
    const int pp = tid & 31;        // p = pp+1
    const float* xb = x + (size_t)(bs + s1) * 64;
    const int j = 2 * pp;
    float xm1 = (j == 0)  ? 0.f : xb[j - 1];
    float x0  = xb[j];
    float x1  = xb[j + 1];
    float xp2 = (j == 62) ? 0.f : xb[j + 2];

    // ---- conv2 weight frags issued now; latency hides under conv1 arithmetic ----
    bf16x8 af[3][4];
#pragma unroll
    for (int t = 0; t < 3; ++t)
#pragma unroll
        for (int mt = 0; mt < 4; ++mt)
            af[t][mt] = *(const bf16x8*)(w2b + (size_t)(t * 64 + mt * 16 + lr) * 32 + lq * 8);
    f32x4 bias2[4];
#pragma unroll
    for (int mt = 0; mt < 4; ++mt)
        bias2[mt] = *(const f32x4*)(b2 + mt * 16 + lq * 4);

    // ---- conv1 + relu + pool2 -> c1T; thread = (sample, p-row), 32x32 = 1024 ----
    {
        u16* sbase = c1h + s1 * 1384;
        if (pp == 0 || pp == 31) {      // halo rows 0 and 33
            uint4 z = make_uint4(0, 0, 0, 0);
            uint4* zr = (uint4*)(sbase + (pp == 0 ? 0 : 33) * 40);
            zr[0] = z; zr[1] = z; zr[2] = z; zr[3] = z;
        }
        u32 row[16];
#pragma unroll
        for (int icp = 0; icp < 16; ++icp) {
            float v[2];
#pragma unroll
            for (int h2 = 0; h2 < 2; ++h2) {
                int ic = icp * 2 + h2;
                // wave-uniform indices -> scalar loads on the s-pipe
                float wa = w1[ic * 3], wb = w1[ic * 3 + 1], wc = w1[ic * 3 + 2], bb = b1[ic];
                float y0 = bb + wa * xm1 + wb * x0 + wc * x1;
                float y1 = bb + wa * x0  + wb * x1 + wc * xp2;
                v[h2] = fmaxf(fmaxf(y0, y1), 0.f);
            }
            row[icp] = pack_rne(v[0], v[1]);
        }
        uint4* d = (uint4*)(sbase + (1 + pp) * 40);
        d[0] = make_uint4(row[0],  row[1],  row[2],  row[3]);
        d[1] = make_uint4(row[4],  row[5],  row[6],  row[7]);
        d[2] = make_uint4(row[8],  row[9],  row[10], row[11]);
        d[3] = make_uint4(row[12], row[13], row[14], row[15]);
    }
    // NO barrier: conv1 wave wv wrote samples {2wv,2wv+1}; conv2 wave wv reads only those.
    // Same-wave LDS ops are in-order -> RAW safe without __syncthreads.

    // ---- conv2 via MFMA (bias as C-init) + pool -> hT aliased into c1h ----
#pragma unroll
    for (int nt = 0; nt < 4; ++nt) {              // wave wv -> samples 2wv, 2wv+1; two q-halves
        const int s  = wv * 2 + (nt >> 1);
        const int qb = (nt & 1) * 16;
        const u16* bp = c1h + s * 1384 + (qb + lr) * 40 + lq * 8;
        bf16x8 bf0 = *(const bf16x8*)(bp);        // tap t=0
        bf16x8 bf1 = *(const bf16x8*)(bp + 40);   // t=1 (+1 row)
        bf16x8 bf2 = *(const bf16x8*)(bp + 80);   // t=2 (+2 rows)
        const int op = (qb + lr) >> 1;
#pragma unroll
        for (int mt = 0; mt < 4; ++mt) {          // interleaved epilogue: acc live = 4
            f32x4 acc = __builtin_amdgcn_mfma_f32_16x16x32_bf16(af[0][mt], bf0, bias2[mt], 0, 0, 0);
            acc = __builtin_amdgcn_mfma_f32_16x16x32_bf16(af[1][mt], bf1, acc, 0, 0, 0);
            acc = __builtin_amdgcn_mfma_f32_16x16x32_bf16(af[2][mt], bf2, acc, 0, 0, 0);
            float p0 = fmaxf(fmaxf(acc[0], __shfl_xor(acc[0], 1)), 0.f);
            float p1 = fmaxf(fmaxf(acc[1], __shfl_xor(acc[1], 1)), 0.f);
            float p2 = fmaxf(fmaxf(acc[2], __shfl_xor(acc[2], 1)), 0.f);
            float p3 = fmaxf(fmaxf(acc[3], __shfl_xor(acc[3], 1)), 0.f);
            if (!(lane & 1)) {
                *(uint2*)(c1h + s * 1384 + op * 72 + mt * 16 + lq * 4) =
                    make_uint2(pack_rne(p0, p1), pack_rne(p2, p3));
            }
        }
    }
    __syncthreads();   // barrier A: fc reads hT across all samples/waves

    // ---- fc via MFMA on waves 0-3: each wave streams B ONCE (single bf16, 128 KB/block),
    //      applies it to both 16-sample A-tiles ----
    if (wv < 4) {
        const int n0 = wv * 16;
        const float fbias = fcb[n0 + lr];
        f32x4 facc0 = {0.f, 0.f, 0.f, 0.f};
        f32x4 facc1 = {0.f, 0.f, 0.f, 0.f};
        const u16* ab0 = c1h + (size_t)lr * 1384 + lq * 8;
        const u16* ab1 = c1h + (size_t)(16 + lr) * 1384 + lq * 8;
        const u16* bh  = whi + (size_t)(n0 + lr) * 1024 + lq * 8;
#pragma unroll 8
        for (int kc = 0; kc < 32; ++kc) {
            const int aoff = (kc >> 1) * 72 + (kc & 1) * 32;
            bf16x8 a0 = *(const bf16x8*)(ab0 + aoff);
            bf16x8 a1 = *(const bf16x8*)(ab1 + aoff);
            bf16x8 fh = *(const bf16x8*)(bh + kc * 32);
            facc0 = __builtin_amdgcn_mfma_f32_16x16x32_bf16(a0, fh, facc0, 0, 0, 0);
            facc1 = __builtin_amdgcn_mfma_f32_16x16x32_bf16(a1, fh, facc1, 0, 0, 0);
        }
        // D: row = lq*4+r = sample-in-tile, col = n0+lr; per-sample hfl slot (disjoint from hT)
#pragma unroll
        for (int r = 0; r < 4; ++r) {
            ((float*)(c1h + (size_t)(lq * 4 + r) * 1384 + 1152))[n0 + lr] =
                fmaxf(facc0[r] + fbias, 0.f);
            ((float*)(c1h + (size_t)(16 + lq * 4 + r) * 1384 + 1152))[n0 + lr] =
                fmaxf(facc1[r] + fbias, 0.f);
        }
    }
    __syncthreads();   // barrier B: epilogue reads hfl from fc waves

    // ---- epilogue on ALL 16 waves: wave -> samples wv*2 + {0,1}, 4 lanes per sample ----
    if (lane < 8) {
        const int L = lane & 3;
        const int s = wv * 2 + (lane >> 2);
        const float* hfl = (const float*)(c1h + (size_t)s * 1384 + 1152);

        float a0 = 0.f, a1 = 0.f, a2 = 0.f, a3 = 0.f;
#pragma unroll
        for (int i2 = 0; i2 < 4; ++i2) {
            float4 hv = *(const float4*)(hfl + L * 16 + i2 * 4);
#pragma unroll
            for (int c = 0; c < 4; ++c) {
                int ff = L * 16 + i2 * 4 + c;
                float4 pw = *(const float4*)&prews[ff * 4];
                float hx = (c == 0) ? hv.x : (c == 1) ? hv.y : (c == 2) ? hv.z : hv.w;
                a0 = fmaf(hx, pw.x, a0);
                a1 = fmaf(hx, pw.y, a1);
                a2 = fmaf(hx, pw.z, a2);
                a3 = fmaf(hx, pw.w, a3);
            }
        }
        a0 += __shfl_xor(a0, 1); a0 += __shfl_xor(a0, 2);
        a1 += __shfl_xor(a1, 1); a1 += __shfl_xor(a1, 2);
        a2 += __shfl_xor(a2, 1); a2 += __shfl_xor(a2, 2);
        a3 += __shfl_xor(a3, 1); a3 += __shfl_xor(a3, 2);

        const float HP = 1.5707963267948966f;
        float qin[4] = { fast_tanh(a0 + preb[0]) * HP, fast_tanh(a1 + preb[1]) * HP,
                         fast_tanh(a2 + preb[2]) * HP, fast_tanh(a3 + preb[3]) * HP };

        float va[4], vb[4];
        const float RS = 0.70710678118654752f;
#pragma unroll
        for (int w = 0; w < 4; ++w) {
            float sw, cw;
            __sincosf(qin[w] * 0.5f, &sw, &cw);
            va[w] = (cw - sw) * RS;
            vb[w] = (sw + cw) * RS;
        }
        float sv[16];
#pragma unroll
        for (int jj = 0; jj < 16; ++jj) {
            float t = (jj & 8) ? vb[0] : va[0];
            t *= (jj & 4) ? vb[1] : va[1];
            t *= (jj & 2) ? vb[2] : va[2];
            t *= (jj & 1) ? vb[3] : va[3];
            sv[jj] = t;
        }
        float z0 = 0.f, z1 = 0.f, z2 = 0.f, z3 = 0.f;
#pragma unroll
        for (int rr = 0; rr < 4; ++rr) {
            const int r = L * 4 + rr;
            float m = 0.f;
#pragma unroll
            for (int jj = 0; jj < 16; ++jj) m = fmaf(Ms[r][jj], sv[jj], m);
            float p = m * m;
            z0 += (r & 8) ? -p : p;
            z1 += (r & 4) ? -p : p;
            z2 += (r & 2) ? -p : p;
            z3 += (r & 1) ? -p : p;
        }
        z0 += __shfl_xor(z0, 1); z0 += __shfl_xor(z0, 2);
        z1 += __shfl_xor(z1, 1); z1 += __shfl_xor(z1, 2);
        z2 += __shfl_xor(z2, 1); z2 += __shfl_xor(z2, 2);
        z3 += __shfl_xor(z3, 1); z3 += __shfl_xor(z3, 2);

        if (L == 0) {
            float t = postb[0] + z0 * postw[0] + z1 * postw[1] + z2 * postw[2] + z3 * postw[3];
            out[bs + s] = 1.f / (1.f + __expf(-t));
        }
    }
}

extern "C" void kernel_launch(void* const* d_in, const int* in_sizes, int n_in,
                              void* d_out, int out_size, void* d_ws, size_t ws_size,
                              hipStream_t stream) {
    const float* x     = (const float*)d_in[0];
    const float* w1    = (const float*)d_in[1];
    const float* b1    = (const float*)d_in[2];
    const float* w2    = (const float*)d_in[3];
    const float* b2    = (const float*)d_in[4];
    const float* fcw   = (const float*)d_in[5];
    const float* fcb   = (const float*)d_in[6];
    const float* prew  = (const float*)d_in[7];
    const float* preb  = (const float*)d_in[8];
    const float* qp    = (const float*)d_in[9];
    const float* postw = (const float*)d_in[10];
    const float* postb = (const float*)d_in[11];
    float* out = (float*)d_out;

    u16*   fwhi = (u16*)d_ws;                           // 64*1024 bf16 = 128 KiB
    float* Mg   = (float*)((char*)d_ws + 131072);       // 1 KiB
    u16*   w2b  = (u16*)((char*)d_ws + 132096);         // 12 KiB

    const int B = in_sizes[0] / 64;   // 32768

    prep_kernel<<<dim3(64), dim3(256), 0, stream>>>(fcw, w2, qp, fwhi, w2b, Mg);
    fused_kernel<<<dim3(B / 32), dim3(1024), 0, stream>>>(x, w1, b1, w2b, b2,
                                                          fwhi, fcb, prew, preb,
                                                          postw, postb, Mg, out);
}

// Round 15
// 142.500 us; speedup vs baseline: 1.1311x; 1.0175x over previous
//
#include <hip/hip_runtime.h>
#include <math.h>

typedef unsigned short u16;
typedef unsigned int u32;
typedef __attribute__((ext_vector_type(8))) short bf16x8;   // 8 bf16 = 4 VGPR (MFMA A/B frag)
typedef __attribute__((ext_vector_type(4))) float f32x4;    // MFMA C/D frag
typedef __attribute__((ext_vector_type(2))) float f32x2;    // packed fp32 pair (v_pk_fma_f32)

__device__ __forceinline__ u16 f32_to_bf16(float f) {
    u32 u = __float_as_uint(f);
    u32 r = u + 0x7FFFu + ((u >> 16) & 1u);   // round-to-nearest-even
    return (u16)(r >> 16);
}
__device__ __forceinline__ u32 pack2(u16 a, u16 b) { return (u32)a | ((u32)b << 16); }

// RNE-rounded bf16 pair pack via v_perm
__device__ __forceinline__ u32 rne_bits(float f) {
    u32 u = __float_as_uint(f);
    return u + 0x7FFFu + ((u >> 16) & 1u);
}
__device__ __forceinline__ u32 pack_rne(float a, float b) {
    return __builtin_amdgcn_perm(rne_bits(b), rne_bits(a), 0x07060302u);
}

// fast tanh via hardware exp
__device__ __forceinline__ float fast_tanh(float x) {
    float e = __expf(2.f * x);
    return 1.f - 2.f / (e + 1.f);
}

// ---------------- quantum gate helpers (prep only; precise libm) ----------------
template<int STRIDE>
__device__ __forceinline__ void ry_gate(float st[16], float theta) {
    float s, c;
    sincosf(theta * 0.5f, &s, &c);
#pragma unroll
    for (int i = 0; i < 16; ++i) {
        if (i & STRIDE) continue;
        float s0 = st[i], s1 = st[i | STRIDE];
        st[i]          = c * s0 - s * s1;
        st[i | STRIDE] = fmaf(s, s0, c * s1);
    }
}
template<int CS, int TS>
__device__ __forceinline__ void cnot_gate(float st[16]) {
#pragma unroll
    for (int i = 0; i < 16; ++i) {
        if ((i & CS) && !(i & TS)) {
            float tmp = st[i]; st[i] = st[i | TS]; st[i | TS] = tmp;
        }
    }
}

// ---------------- Prep: fcw transpose->bf16, w2->bf16 frag layout, circuit matrix M ----------
// whi: [f][k = op*64+oc] (k_ref = oc*16+op). w2b: [(t*64+oc)*32+ic] bf16.
__global__ __launch_bounds__(256) void prep_kernel(
    const float* __restrict__ fcw, const float* __restrict__ w2,
    const float* __restrict__ qp,
    u16* __restrict__ whi, u16* __restrict__ w2b, float* __restrict__ Mg)
{
    const int f  = blockIdx.x;         // 0..63
    const int k0 = threadIdx.x * 4;    // 0..1020
    u16 hv[4];
#pragma unroll
    for (int i = 0; i < 4; ++i) {
        int k  = k0 + i;
        int op = k >> 6, oc = k & 63;
        hv[i] = f32_to_bf16(fcw[(size_t)(oc * 16 + op) * 64 + f]);
    }
    *(uint2*)(whi + (size_t)f * 1024 + k0) = make_uint2(pack2(hv[0], hv[1]), pack2(hv[2], hv[3]));

    if (threadIdx.x < 96) {
        const int j  = threadIdx.x;
        const int ic = j / 3, t = j - ic * 3;
        w2b[(t * 64 + f) * 32 + ic] = f32_to_bf16(w2[f * 96 + j]);
    }

    if (blockIdx.x == 0 && threadIdx.x < 16) {
        const int j = threadIdx.x;
        float st[16];
#pragma unroll
        for (int i = 0; i < 16; ++i) st[i] = (i == j) ? 1.f : 0.f;
        for (int k = 0; k < 6; ++k) {
            cnot_gate<8, 4>(st);   // CNOT(0,1)
            cnot_gate<2, 1>(st);   // CNOT(2,3)
            cnot_gate<4, 2>(st);   // CNOT(1,2)
            ry_gate<8>(st, qp[k * 4 + 0]);
            ry_gate<4>(st, qp[k * 4 + 1]);
            ry_gate<2>(st, qp[k * 4 + 2]);
            ry_gate<1>(st, qp[k * 4 + 3]);
        }
#pragma unroll
        for (int i = 0; i < 16; ++i) Mg[i * 16 + j] = st[i];
    }
}

// ---------------- Fused: conv1 -> conv2(MFMA) -> fc(MFMA) -> quantum epilogue ----------------
// R15 = R14 champion + two local edits:
//  (1) conv1 inner math as f32x2 packed pairs (y0,y1 positions) -> v_pk_fma_f32 (~40% fewer
//      conv1 VALU insts if LLVM packs; harmless otherwise).
//  (2) fc on 2 waves x 32 features with 2x2 register tiling: per kc 2 A-reads + 2 B-loads +
//      4 MFMA. Total fc ds_read_b128 halves (256->128/block, ~12cyc each, serialized per-CU
//      LDS); B-traffic (128 KB/block) and MFMA count (256) unchanged.
// Carried R14 invariants: no barrier before conv2 (conv1 wave wv writes exactly the samples
// {2wv,2wv+1} conv2 wave wv reads - same-wave in-order LDS); conv2 weight frags issued
// after x loads, before conv1 arithmetic (vmcnt in-order). Loose cap (1024,4): no spill.
// Spill canary: WRITE_SIZE ~0.13 MB. Per-sample block in c1h (1384 u16): c1T rows p[0,34)
// stride 40 (halo rows 0,33 zero); hT aliased (same-wave read-before-write) op-chunk
// stride 72; hfl f32[64] at u16 offset 1152.
__global__ __launch_bounds__(1024, 4) void fused_kernel(
    const float* __restrict__ x,
    const float* __restrict__ w1, const float* __restrict__ b1,
    const u16* __restrict__ w2b, const float* __restrict__ b2,
    const u16* __restrict__ whi,
    const float* __restrict__ fcb,
    const float* __restrict__ prew, const float* __restrict__ preb,
    const float* __restrict__ postw, const float* __restrict__ postb,
    const float* __restrict__ Mg,
    float* __restrict__ out)
{
    __shared__ __align__(16) u16 c1h[32 * 1384];   // 88.6 KB
    __shared__ float prews[256];                   // 1 KB
    __shared__ float Ms[16][17];                   // 1.1 KB

    const int tid  = threadIdx.x;
    const int bs   = blockIdx.x * 32;
    const int wv   = tid >> 6, lane = tid & 63;
    const int lr   = lane & 15, lq = lane >> 4;

    // ---- stage small tables (consumed after barrier B -> visible) ----
    if (tid < 256) {
        prews[tid] = prew[tid];
        Ms[tid >> 4][tid & 15] = Mg[tid];
    }

    // ---- x loads FIRST (vmcnt in-order: conv1's wait won't drain later af loads) ----
    const int s1 = tid >> 5;        // 0..31
    const int pp = tid & 31;        // p = pp+1
    const float* xb = x + (size_t)(bs + s1) * 64;
    const int j = 2 * pp;
    float xm1 = (j == 0)  ? 0.f : xb[j - 1];
    float x0  = xb[j];
    float x1  = xb[j + 1];
    float xp2 = (j == 62) ? 0.f : xb[j + 2];

    // ---- conv2 weight frags issued now; latency hides under conv1 arithmetic ----
    bf16x8 af[3][4];
#pragma unroll
    for (int t = 0; t < 3; ++t)
#pragma unroll
        for (int mt = 0; mt < 4; ++mt)
            af[t][mt] = *(const bf16x8*)(w2b + (size_t)(t * 64 + mt * 16 + lr) * 32 + lq * 8);
    f32x4 bias2[4];
#pragma unroll
    for (int mt = 0; mt < 4; ++mt)
        bias2[mt] = *(const f32x4*)(b2 + mt * 16 + lq * 4);

    // ---- conv1 + relu + pool2 -> c1T; packed-pair math (y0,y1) -> v_pk_fma_f32 ----
    {
        u16* sbase = c1h + s1 * 1384;
        if (pp == 0 || pp == 31) {      // halo rows 0 and 33
            uint4 z = make_uint4(0, 0, 0, 0);
            uint4* zr = (uint4*)(sbase + (pp == 0 ? 0 : 33) * 40);
            zr[0] = z; zr[1] = z; zr[2] = z; zr[3] = z;
        }
        const f32x2 A1 = {xm1, x0};
        const f32x2 A2 = {x0,  x1};
        const f32x2 A3 = {x1,  xp2};
        u32 row[16];
#pragma unroll
        for (int icp = 0; icp < 16; ++icp) {
            float v[2];
#pragma unroll
            for (int h2 = 0; h2 < 2; ++h2) {
                int ic = icp * 2 + h2;
                // wave-uniform indices -> scalar loads on the s-pipe
                float wa = w1[ic * 3], wb = w1[ic * 3 + 1], wc = w1[ic * 3 + 2], bb = b1[ic];
                f32x2 Y = {bb, bb};
                Y += wa * A1;
                Y += wb * A2;
                Y += wc * A3;
                v[h2] = fmaxf(fmaxf(Y.x, Y.y), 0.f);   // pool + relu (v_max3)
            }
            row[icp] = pack_rne(v[0], v[1]);
        }
        uint4* d = (uint4*)(sbase + (1 + pp) * 40);
        d[0] = make_uint4(row[0],  row[1],  row[2],  row[3]);
        d[1] = make_uint4(row[4],  row[5],  row[6],  row[7]);
        d[2] = make_uint4(row[8],  row[9],  row[10], row[11]);
        d[3] = make_uint4(row[12], row[13], row[14], row[15]);
    }
    // NO barrier: conv1 wave wv wrote samples {2wv,2wv+1}; conv2 wave wv reads only those.
    // Same-wave LDS ops are in-order -> RAW safe without __syncthreads.

    // ---- conv2 via MFMA (bias as C-init) + pool -> hT aliased into c1h ----
#pragma unroll
    for (int nt = 0; nt < 4; ++nt) {              // wave wv -> samples 2wv, 2wv+1; two q-halves
        const int s  = wv * 2 + (nt >> 1);
        const int qb = (nt & 1) * 16;
        const u16* bp = c1h + s * 1384 + (qb + lr) * 40 + lq * 8;
        bf16x8 bf0 = *(const bf16x8*)(bp);        // tap t=0
        bf16x8 bf1 = *(const bf16x8*)(bp + 40);   // t=1 (+1 row)
        bf16x8 bf2 = *(const bf16x8*)(bp + 80);   // t=2 (+2 rows)
        const int op = (qb + lr) >> 1;
#pragma unroll
        for (int mt = 0; mt < 4; ++mt) {          // interleaved epilogue: acc live = 4
            f32x4 acc = __builtin_amdgcn_mfma_f32_16x16x32_bf16(af[0][mt], bf0, bias2[mt], 0, 0, 0);
            acc = __builtin_amdgcn_mfma_f32_16x16x32_bf16(af[1][mt], bf1, acc, 0, 0, 0);
            acc = __builtin_amdgcn_mfma_f32_16x16x32_bf16(af[2][mt], bf2, acc, 0, 0, 0);
            float p0 = fmaxf(fmaxf(acc[0], __shfl_xor(acc[0], 1)), 0.f);
            float p1 = fmaxf(fmaxf(acc[1], __shfl_xor(acc[1], 1)), 0.f);
            float p2 = fmaxf(fmaxf(acc[2], __shfl_xor(acc[2], 1)), 0.f);
            float p3 = fmaxf(fmaxf(acc[3], __shfl_xor(acc[3], 1)), 0.f);
            if (!(lane & 1)) {
                *(uint2*)(c1h + s * 1384 + op * 72 + mt * 16 + lq * 4) =
                    make_uint2(pack_rne(p0, p1), pack_rne(p2, p3));
            }
        }
    }
    __syncthreads();   // barrier A: fc reads hT across all samples/waves

    // ---- fc via MFMA on waves 0-1: wave wv -> features wv*32..+31, 2x2 register tile.
    //      Per kc: 2 A-reads + 2 B-loads + 4 MFMA -> total fc ds_reads halved vs 4-wave. ----
    if (wv < 2) {
        const int n0 = wv * 32;
        f32x4 acc00 = {0.f, 0.f, 0.f, 0.f};   // [tile0][fgrp0]
        f32x4 acc01 = {0.f, 0.f, 0.f, 0.f};   // [tile0][fgrp1]
        f32x4 acc10 = {0.f, 0.f, 0.f, 0.f};   // [tile1][fgrp0]
        f32x4 acc11 = {0.f, 0.f, 0.f, 0.f};   // [tile1][fgrp1]
        const u16* ab0 = c1h + (size_t)lr * 1384 + lq * 8;
        const u16* ab1 = c1h + (size_t)(16 + lr) * 1384 + lq * 8;
        const u16* bh0 = whi + (size_t)(n0 + lr) * 1024 + lq * 8;
        const u16* bh1 = whi + (size_t)(n0 + 16 + lr) * 1024 + lq * 8;
#pragma unroll 8
        for (int kc = 0; kc < 32; ++kc) {
            const int aoff = (kc >> 1) * 72 + (kc & 1) * 32;
            bf16x8 a0 = *(const bf16x8*)(ab0 + aoff);
            bf16x8 a1 = *(const bf16x8*)(ab1 + aoff);
            bf16x8 f0 = *(const bf16x8*)(bh0 + kc * 32);
            bf16x8 f1 = *(const bf16x8*)(bh1 + kc * 32);
            acc00 = __builtin_amdgcn_mfma_f32_16x16x32_bf16(a0, f0, acc00, 0, 0, 0);
            acc01 = __builtin_amdgcn_mfma_f32_16x16x32_bf16(a0, f1, acc01, 0, 0, 0);
            acc10 = __builtin_amdgcn_mfma_f32_16x16x32_bf16(a1, f0, acc10, 0, 0, 0);
            acc11 = __builtin_amdgcn_mfma_f32_16x16x32_bf16(a1, f1, acc11, 0, 0, 0);
        }
        // D: row = lq*4+r = sample-in-tile, col = feature; per-sample hfl slot (disjoint from hT)
        const float fb0 = fcb[n0 + lr];
        const float fb1 = fcb[n0 + 16 + lr];
#pragma unroll
        for (int r = 0; r < 4; ++r) {
            float* h0 = (float*)(c1h + (size_t)(lq * 4 + r) * 1384 + 1152);
            float* h1 = (float*)(c1h + (size_t)(16 + lq * 4 + r) * 1384 + 1152);
            h0[n0 + lr]      = fmaxf(acc00[r] + fb0, 0.f);
            h0[n0 + 16 + lr] = fmaxf(acc01[r] + fb1, 0.f);
            h1[n0 + lr]      = fmaxf(acc10[r] + fb0, 0.f);
            h1[n0 + 16 + lr] = fmaxf(acc11[r] + fb1, 0.f);
        }
    }
    __syncthreads();   // barrier B: epilogue reads hfl from fc waves

    // ---- epilogue on ALL 16 waves: wave -> samples wv*2 + {0,1}, 4 lanes per sample ----
    if (lane < 8) {
        const int L = lane & 3;
        const int s = wv * 2 + (lane >> 2);
        const float* hfl = (const float*)(c1h + (size_t)s * 1384 + 1152);

        float a0 = 0.f, a1 = 0.f, a2 = 0.f, a3 = 0.f;
#pragma unroll
        for (int i2 = 0; i2 < 4; ++i2) {
            float4 hv = *(const float4*)(hfl + L * 16 + i2 * 4);
#pragma unroll
            for (int c = 0; c < 4; ++c) {
                int ff = L * 16 + i2 * 4 + c;
                float4 pw = *(const float4*)&prews[ff * 4];
                float hx = (c == 0) ? hv.x : (c == 1) ? hv.y : (c == 2) ? hv.z : hv.w;
                a0 = fmaf(hx, pw.x, a0);
                a1 = fmaf(hx, pw.y, a1);
                a2 = fmaf(hx, pw.z, a2);
                a3 = fmaf(hx, pw.w, a3);
            }
        }
        a0 += __shfl_xor(a0, 1); a0 += __shfl_xor(a0, 2);
        a1 += __shfl_xor(a1, 1); a1 += __shfl_xor(a1, 2);
        a2 += __shfl_xor(a2, 1); a2 += __shfl_xor(a2, 2);
        a3 += __shfl_xor(a3, 1); a3 += __shfl_xor(a3, 2);

        const float HP = 1.5707963267948966f;
        float qin[4] = { fast_tanh(a0 + preb[0]) * HP, fast_tanh(a1 + preb[1]) * HP,
                         fast_tanh(a2 + preb[2]) * HP, fast_tanh(a3 + preb[3]) * HP };

        float va[4], vb[4];
        const float RS = 0.70710678118654752f;
#pragma unroll
        for (int w = 0; w < 4; ++w) {
            float sw, cw;
            __sincosf(qin[w] * 0.5f, &sw, &cw);
            va[w] = (cw - sw) * RS;
            vb[w] = (sw + cw) * RS;
        }
        float sv[16];
#pragma unroll
        for (int jj = 0; jj < 16; ++jj) {
            float t = (jj & 8) ? vb[0] : va[0];
            t *= (jj & 4) ? vb[1] : va[1];
            t *= (jj & 2) ? vb[2] : va[2];
            t *= (jj & 1) ? vb[3] : va[3];
            sv[jj] = t;
        }
        float z0 = 0.f, z1 = 0.f, z2 = 0.f, z3 = 0.f;
#pragma unroll
        for (int rr = 0; rr < 4; ++rr) {
            const int r = L * 4 + rr;
            float m = 0.f;
#pragma unroll
            for (int jj = 0; jj < 16; ++jj) m = fmaf(Ms[r][jj], sv[jj], m);
            float p = m * m;
            z0 += (r & 8) ? -p : p;
            z1 += (r & 4) ? -p : p;
            z2 += (r & 2) ? -p : p;
            z3 += (r & 1) ? -p : p;
        }
        z0 += __shfl_xor(z0, 1); z0 += __shfl_xor(z0, 2);
        z1 += __shfl_xor(z1, 1); z1 += __shfl_xor(z1, 2);
        z2 += __shfl_xor(z2, 1); z2 += __shfl_xor(z2, 2);
        z3 += __shfl_xor(z3, 1); z3 += __shfl_xor(z3, 2);

        if (L == 0) {
            float t = postb[0] + z0 * postw[0] + z1 * postw[1] + z2 * postw[2] + z3 * postw[3];
            out[bs + s] = 1.f / (1.f + __expf(-t));
        }
    }
}

extern "C" void kernel_launch(void* const* d_in, const int* in_sizes, int n_in,
                              void* d_out, int out_size, void* d_ws, size_t ws_size,
                              hipStream_t stream) {
    const float* x     = (const float*)d_in[0];
    const float* w1    = (const float*)d_in[1];
    const float* b1    = (const float*)d_in[2];
    const float* w2    = (const float*)d_in[3];
    const float* b2    = (const float*)d_in[4];
    const float* fcw   = (const float*)d_in[5];
    const float* fcb   = (const float*)d_in[6];
    const float* prew  = (const float*)d_in[7];
    const float* preb  = (const float*)d_in[8];
    const float* qp    = (const float*)d_in[9];
    const float* postw = (const float*)d_in[10];
    const float* postb = (const float*)d_in[11];
    float* out = (float*)d_out;

    u16*   fwhi = (u16*)d_ws;                           // 64*1024 bf16 = 128 KiB
    float* Mg   = (float*)((char*)d_ws + 131072);       // 1 KiB
    u16*   w2b  = (u16*)((char*)d_ws + 132096);         // 12 KiB

    const int B = in_sizes[0] / 64;   // 32768

    prep_kernel<<<dim3(64), dim3(256), 0, stream>>>(fcw, w2, qp, fwhi, w2b, Mg);
    fused_kernel<<<dim3(B / 32), dim3(1024), 0, stream>>>(x, w1, b1, w2b, b2,
                                                          fwhi, fcb, prew, preb,
                                                          postw, postb, Mg, out);
}